// Round 2
// baseline (189.262 us; speedup 1.0000x reference)
//
#include <hip/hip_runtime.h>
#include <hip/hip_bf16.h>

typedef __attribute__((ext_vector_type(8))) short short8;
typedef __attribute__((ext_vector_type(4))) float f32x4;

#define BATCH 524288
#define KD 512
#define OD 32
#define RPB 256            // rows per block (4 waves x 4 tiles x 16 rows)
#define NB1 (BATCH / RPB)  // 2048 blocks
#define WPAD 520           // padded LDS row stride (bf16 elems) to break bank conflicts

__device__ __forceinline__ short bf16b(float f) {
  __hip_bfloat16 h = __float2bfloat16(f);
  return __builtin_bit_cast(short, h);
}

// K1: per-block 256 rows: y = x * W^T (bf16 MFMA), rowmax over 32 outs,
// online (max,sum) partial LSE -> partial[2*blockIdx]
__global__ __launch_bounds__(256, 4) void k1_gemm_lse(const float* __restrict__ x,
                                                      const float* __restrict__ W,
                                                      float* __restrict__ partial) {
  __shared__ __align__(16) short Wlds[OD * WPAD];
  __shared__ float pm[4], ps[4];
  const int tid = threadIdx.x;

  // Stage W (32x512 f32) as bf16 into LDS, padded stride.
#pragma unroll
  for (int j = 0; j < 16; ++j) {
    int e = tid + j * 256;  // float4 index, 4096 total
    f32x4 w = *reinterpret_cast<const f32x4*>(W + (size_t)e * 4);
    int o = e >> 7;           // row (out-feature)
    int k = (e & 127) << 2;   // col
    short* dst = &Wlds[o * WPAD + k];
    dst[0] = bf16b(w[0]); dst[1] = bf16b(w[1]);
    dst[2] = bf16b(w[2]); dst[3] = bf16b(w[3]);
  }
  __syncthreads();

  const int wave = tid >> 6;
  const int lane = tid & 63;
  const int l15 = lane & 15;
  const int grp = lane >> 4;  // 0..3

  float runM = -INFINITY, runS = 0.0f;

  for (int t = 0; t < 4; ++t) {
    const int row = blockIdx.x * RPB + t * 64 + wave * 16 + l15;
    const float* xp = x + (size_t)row * KD + grp * 8;
    f32x4 acc0 = {0.f, 0.f, 0.f, 0.f};
    f32x4 acc1 = {0.f, 0.f, 0.f, 0.f};
#pragma unroll 4
    for (int k0 = 0; k0 < KD; k0 += 32) {
      f32x4 a0 = *reinterpret_cast<const f32x4*>(xp + k0);
      f32x4 a1 = *reinterpret_cast<const f32x4*>(xp + k0 + 4);
      short8 af;
      af[0] = bf16b(a0[0]); af[1] = bf16b(a0[1]);
      af[2] = bf16b(a0[2]); af[3] = bf16b(a0[3]);
      af[4] = bf16b(a1[0]); af[5] = bf16b(a1[1]);
      af[6] = bf16b(a1[2]); af[7] = bf16b(a1[3]);
      // B operand: B[k][col] = W[col][k]; lane holds k = k0+grp*8+j, col = l15 (+16)
      short8 b0 = *reinterpret_cast<const short8*>(&Wlds[l15 * WPAD + k0 + grp * 8]);
      short8 b1 = *reinterpret_cast<const short8*>(&Wlds[(16 + l15) * WPAD + k0 + grp * 8]);
      acc0 = __builtin_amdgcn_mfma_f32_16x16x32_bf16(af, b0, acc0, 0, 0, 0);
      acc1 = __builtin_amdgcn_mfma_f32_16x16x32_bf16(af, b1, acc1, 0, 0, 0);
    }
    // D layout: lane holds D[grp*4 + r][l15] (acc0: outs 0-15, acc1: outs 16-31)
    float v0 = fmaxf(acc0[0], acc1[0]);
    float v1 = fmaxf(acc0[1], acc1[1]);
    float v2 = fmaxf(acc0[2], acc1[2]);
    float v3 = fmaxf(acc0[3], acc1[3]);
#pragma unroll
    for (int mask = 1; mask < 16; mask <<= 1) {
      v0 = fmaxf(v0, __shfl_xor(v0, mask));
      v1 = fmaxf(v1, __shfl_xor(v1, mask));
      v2 = fmaxf(v2, __shfl_xor(v2, mask));
      v3 = fmaxf(v3, __shfl_xor(v3, mask));
    }
    // v_r now = rowmax of row (base + grp*4 + r), uniform within each 16-lane group
    float tmax = fmaxf(fmaxf(v0, v1), fmaxf(v2, v3));
    float wmax = fmaxf(tmax, __shfl_xor(tmax, 16));
    wmax = fmaxf(wmax, __shfl_xor(wmax, 32));
    float s = __expf(v0 - wmax) + __expf(v1 - wmax) +
              __expf(v2 - wmax) + __expf(v3 - wmax);
#pragma unroll
    for (int mask = 1; mask < 64; mask <<= 1) s += __shfl_xor(s, mask);
    s *= (1.0f / 16.0f);  // each row counted 16x across the wave
    float nM = fmaxf(runM, wmax);
    runS = runS * __expf(runM - nM) + s * __expf(wmax - nM);
    runM = nM;
  }

  if (lane == 0) { pm[wave] = runM; ps[wave] = runS; }
  __syncthreads();
  if (tid == 0) {
    float M = fmaxf(fmaxf(pm[0], pm[1]), fmaxf(pm[2], pm[3]));
    float S = ps[0] * __expf(pm[0] - M) + ps[1] * __expf(pm[1] - M) +
              ps[2] * __expf(pm[2] - M) + ps[3] * __expf(pm[3] - M);
    partial[2 * blockIdx.x] = M;
    partial[2 * blockIdx.x + 1] = S;
  }
}

// K2: merge 2048 (max,sum) pairs -> l2 scalar
__global__ __launch_bounds__(256) void k2_reduce(const float* __restrict__ partial,
                                                 float* __restrict__ sc) {
  const int tid = threadIdx.x;
  const int wave = tid >> 6;
  const int lane = tid & 63;
  float Ml[8], Sl[8];
  float m = -INFINITY;
#pragma unroll
  for (int j = 0; j < 8; ++j) {
    int i = tid + j * 256;
    Ml[j] = partial[2 * i];
    Sl[j] = partial[2 * i + 1];
    m = fmaxf(m, Ml[j]);
  }
#pragma unroll
  for (int mask = 1; mask < 64; mask <<= 1) m = fmaxf(m, __shfl_xor(m, mask));
  __shared__ float lm[4], lsum[4];
  if (lane == 0) lm[wave] = m;
  __syncthreads();
  float gM = fmaxf(fmaxf(lm[0], lm[1]), fmaxf(lm[2], lm[3]));
  float s = 0.0f;
#pragma unroll
  for (int j = 0; j < 8; ++j) s += Sl[j] * __expf(Ml[j] - gM);
#pragma unroll
  for (int mask = 1; mask < 64; mask <<= 1) s += __shfl_xor(s, mask);
  if (lane == 0) lsum[wave] = s;
  __syncthreads();
  if (tid == 0) {
    float S = lsum[0] + lsum[1] + lsum[2] + lsum[3];
    // l2 = l1 + log(B), B = 2^19
    sc[0] = gM + logf(S) + 19.0f * 0.69314718055994530942f;
  }
}

// K3: broadcast-fill output [B,1]
__global__ __launch_bounds__(256) void k3_fill(float* __restrict__ out,
                                               const float* __restrict__ sc) {
  float v = sc[0];
  size_t i = ((size_t)blockIdx.x * 256 + threadIdx.x) * 4;
  f32x4 o = {v, v, v, v};
  *reinterpret_cast<f32x4*>(out + i) = o;
}

extern "C" void kernel_launch(void* const* d_in, const int* in_sizes, int n_in,
                              void* d_out, int out_size, void* d_ws, size_t ws_size,
                              hipStream_t stream) {
  const float* x = (const float*)d_in[0];
  const float* W = (const float*)d_in[1];
  float* out = (float*)d_out;
  float* ws = (float*)d_ws;

  k1_gemm_lse<<<NB1, 256, 0, stream>>>(x, W, ws);
  k2_reduce<<<1, 256, 0, stream>>>(ws, ws + 2 * NB1);
  k3_fill<<<BATCH / 1024, 256, 0, stream>>>(out, ws + 2 * NB1);
}